// Round 12
// baseline (237.216 us; speedup 1.0000x reference)
//
#include <hip/hip_runtime.h>

// EMA along T: y[0]=x[0]; y[t] = s*x[t] + (1-s)*y[t-1].
// x: [B, C, T] f32, weights: [C] f32 (clamped to [0,1]). B=16, C=512, T=4096.
//
// ONE 64-lane wave owns a full row (4096 elems = 16 chunks of 256; lane l
// holds float4 at chunk*64 + l -> every load/store is 64x16B contiguous).
// All 16 loads are issued UP FRONT (64 KB/wave in flight); the row is then
// processed as 4 tiles of 4 chunks, each tile: per-chunk 3-FMA local scan ->
// 6-step weighted Hillis-Steele shuffle scan (step weight a^4, 4 chunks
// interleaved) -> fixup with the EXACT running carry E (advanced per chunk,
// weight a^256, via __shfl broadcast of chunk totals) -> non-temporal
// stores. Later tiles' loads land under earlier tiles' compute (compiler
// emits progressive vmcnt waits), and stores overlap the next tile's
// compute -> continuous memory traffic instead of load/compute/store
// convoy phases. No LDS, no barriers, no halo (exact everywhere).
// __launch_bounds__(256,4) allows ~90 VGPR so the 16 loads are NOT
// re-rolled (round-6 lesson: default scheduling collapsed them to 36 VGPR
// and killed the MLP).

constexpr int T_LEN = 4096;
constexpr int C_LEN = 512;
constexpr int BLOCK = 256;            // 4 independent row-waves per block
constexpr int NCHUNK = 16;            // chunks per row (256 elems each)

typedef float nfloat4 __attribute__((ext_vector_type(4)));

__global__ __launch_bounds__(BLOCK, 4) void ema_row_kernel(
    const float* __restrict__ x,
    const float* __restrict__ w,
    float* __restrict__ y)
{
    const int lane = threadIdx.x & 63;
    const int wv   = threadIdx.x >> 6;
    const int row  = (blockIdx.x << 2) + wv;   // one row per wave
    const int c    = row & (C_LEN - 1);

    float s = w[c];
    s = fminf(fmaxf(s, 0.0f), 1.0f);
    const float a = 1.0f - s;

    const nfloat4* xp = (const nfloat4*)(x + (size_t)row * T_LEN);
    nfloat4*       yp = (nfloat4*)(y + (size_t)row * T_LEN);

    // ---- issue ALL 16 coalesced loads up front (64 KB/wave MLP) ----
    nfloat4 v[NCHUNK];
    #pragma unroll
    for (int m = 0; m < NCHUNK; ++m)
        v[m] = xp[(m << 6) + lane];

    const float a2 = a * a, a3 = a2 * a, a4 = a2 * a2;

    // (a^4)^lane for carry injection
    float powl = 1.0f, tq = a4;
    #pragma unroll
    for (int b = 0; b < 6; ++b) {
        if ((lane >> b) & 1) powl *= tq;
        tq *= tq;
    }
    // a^256 = (a^4)^64 (one chunk's span)
    float a256 = a4;
    #pragma unroll
    for (int q = 0; q < 6; ++q) a256 *= a256;

    float E = 0.0f;   // exact EMA state entering current chunk

    // ---- 4 pipelined tile phases ----
    #pragma unroll
    for (int t = 0; t < 4; ++t) {
        float S[4];

        // per-chunk local scans (zero incoming carry)
        #pragma unroll
        for (int k = 0; k < 4; ++k) {
            const int m = (t << 2) + k;
            float l0 = s * v[m].x;
            if (m == 0 && lane == 0) l0 = v[m].x;   // y0 = x0 identity
            float l1 = fmaf(a, l0, s * v[m].y);
            float l2 = fmaf(a, l1, s * v[m].z);
            float l3 = fmaf(a, l2, s * v[m].w);
            v[m].x = l0; v[m].y = l1; v[m].z = l2; v[m].w = l3;
            S[k] = l3;
        }

        // weighted Hillis-Steele over 64 lanes (step weight a^4)
        float wgt = a4;
        #pragma unroll
        for (int d = 1; d < 64; d <<= 1) {
            #pragma unroll
            for (int k = 0; k < 4; ++k) {
                float up = __shfl_up(S[k], d, 64);
                if (lane >= d) S[k] = fmaf(wgt, up, S[k]);
            }
            wgt *= wgt;
        }

        // fixup with exact running carry + nt-store; advance E per chunk
        #pragma unroll
        for (int k = 0; k < 4; ++k) {
            const int m = (t << 2) + k;
            float Sx   = __shfl_up(S[k], 1, 64);
            float base = (lane == 0) ? 0.0f : Sx;   // within-chunk excl prefix
            float P    = fmaf(powl, E, base);
            nfloat4 o;
            o.x = fmaf(a,  P, v[m].x);
            o.y = fmaf(a2, P, v[m].y);
            o.z = fmaf(a3, P, v[m].z);
            o.w = fmaf(a4, P, v[m].w);
            __builtin_nontemporal_store(o, &yp[(m << 6) + lane]);

            float Tk = __shfl(S[k], 63, 64);        // chunk total
            E = fmaf(a256, E, Tk);
        }
    }
}

extern "C" void kernel_launch(void* const* d_in, const int* in_sizes, int n_in,
                              void* d_out, int out_size, void* d_ws, size_t ws_size,
                              hipStream_t stream) {
    const float* x = (const float*)d_in[0];
    const float* w = (const float*)d_in[1];
    float* y = (float*)d_out;

    const int rows = out_size / T_LEN;    // B*C = 8192
    ema_row_kernel<<<rows / 4, BLOCK, 0, stream>>>(x, w, y);
}

// Round 13
// 232.817 us; speedup vs baseline: 1.0189x; 1.0189x over previous
//
#include <hip/hip_runtime.h>

// EMA along T: y[0]=x[0]; y[t] = s*x[t] + (1-s)*y[t-1].
// x: [B, C, T] f32, weights: [C] f32 (clamped to [0,1]). B=16, C=512, T=4096.
//
// PERSISTENT grid-stride version of the round-10 structure (the fastest so
// far). 2048 blocks (8/CU, all resident, no block turnover); each block
// processes 4 rows: row = g*2048 + blockIdx.x, g = 0..3. Per row, the
// round-10 mapping: 4 waves/block, each lane owns 4 chunks of float4
// (element (k,wv,l,j) = 1024k + 256wv + 4l + j) -> every global access is
// 64x16B contiguous.
//
// The NEXT row's 4 loads are issued BEFORE the current row's scan and
// pinned with sched_barrier(0) (rounds 6/12 showed the compiler otherwise
// sinks/re-rolls them), so stores of row g overlap loads of row g+1 ->
// each wave alternates loads and stores continuously like the 6.3 TB/s
// copy microbenchmark, instead of one-shot load/compute/store/die.
//
// LDS chunk-total buffer is double-buffered on g&1 so each row needs only
// ONE __syncthreads (no WAR hazard: the other buffer's readers all passed
// the previous row's barrier). Non-temporal stores keep y from evicting x
// out of L3.

constexpr int T_LEN = 4096;
constexpr int C_LEN = 512;
constexpr int BLOCK = 256;            // 4 waves
constexpr int NW    = 4;              // waves per block
constexpr int CH    = 4;              // chunks per lane per row
constexpr int GRID  = 2048;           // 8 blocks/CU, all resident
constexpr int GENS  = 4;              // rows per block; GRID*GENS = 8192

typedef float nfloat4 __attribute__((ext_vector_type(4)));

__global__ __launch_bounds__(BLOCK) void ema_persist_kernel(
    const float* __restrict__ x,
    const float* __restrict__ w,
    float* __restrict__ y)
{
    const int tid  = threadIdx.x;
    const int lane = tid & 63;
    const int wv   = tid >> 6;

    __shared__ float tot[2][CH * NW];

    // ---- prologue: load generation-0 row ----
    nfloat4 vc[CH];
    {
        const nfloat4* xp = (const nfloat4*)(x + (size_t)blockIdx.x * T_LEN);
        #pragma unroll
        for (int k = 0; k < CH; ++k)
            vc[k] = xp[(k << 8) + (wv << 6) + lane];
    }

    #pragma unroll
    for (int g = 0; g < GENS; ++g) {
        const int row = g * GRID + blockIdx.x;

        // ---- prefetch next row BEFORE computing this one ----
        nfloat4 vn[CH];
        if (g < GENS - 1) {
            const nfloat4* xn = (const nfloat4*)(x + (size_t)(row + GRID) * T_LEN);
            #pragma unroll
            for (int k = 0; k < CH; ++k)
                vn[k] = xn[(k << 8) + (wv << 6) + lane];
        }
        __builtin_amdgcn_sched_barrier(0);   // pin prefetch issue point

        const int c = row & (C_LEN - 1);
        float s = fminf(fmaxf(w[c], 0.0f), 1.0f);
        const float a = 1.0f - s;
        const float a2 = a * a, a3 = a2 * a, a4 = a2 * a2;

        // ---- per-chunk local scans (zero incoming carry) ----
        float S[CH];
        #pragma unroll
        for (int k = 0; k < CH; ++k) {
            float l0 = s * vc[k].x;
            if (k == 0 && tid == 0) l0 = vc[0].x;    // y0 = x0 (every row)
            float l1 = fmaf(a, l0, s * vc[k].y);
            float l2 = fmaf(a, l1, s * vc[k].z);
            float l3 = fmaf(a, l2, s * vc[k].w);
            vc[k].x = l0; vc[k].y = l1; vc[k].z = l2; vc[k].w = l3;
            S[k] = l3;
        }

        // ---- weighted Hillis-Steele over 64 lanes (step weight a^4) ----
        float wgt = a4;
        #pragma unroll
        for (int d = 1; d < 64; d <<= 1) {
            #pragma unroll
            for (int k = 0; k < CH; ++k) {
                float up = __shfl_up(S[k], d, 64);
                if (lane >= d) S[k] = fmaf(wgt, up, S[k]);
            }
            wgt *= wgt;
        }
        const float a256 = wgt;   // (a^4)^64, one segment's span

        // ---- segment totals through double-buffered LDS ----
        if (lane == 63) {
            #pragma unroll
            for (int k = 0; k < CH; ++k) tot[g & 1][(k << 2) + wv] = S[k];
        }
        __syncthreads();

        float E[CH];
        {
            float R = 0.0f;
            #pragma unroll
            for (int m = 0; m < CH * NW; ++m) {
                if ((m & 3) == wv) E[m >> 2] = R;     // wave-uniform branch
                R = fmaf(a256, R, tot[g & 1][m]);     // LDS broadcast read
            }
        }

        // (a^4)^lane for carry injection
        float powl = 1.0f, tq = a4;
        #pragma unroll
        for (int b = 0; b < 6; ++b) {
            if ((lane >> b) & 1) powl *= tq;
            tq *= tq;
        }

        // ---- fixup + non-temporal coalesced stores ----
        nfloat4* yp = (nfloat4*)(y + (size_t)row * T_LEN);
        #pragma unroll
        for (int k = 0; k < CH; ++k) {
            float Sx   = __shfl_up(S[k], 1, 64);
            float base = (lane == 0) ? 0.0f : Sx;
            float P    = fmaf(powl, E[k], base);
            nfloat4 o;
            o.x = fmaf(a,  P, vc[k].x);
            o.y = fmaf(a2, P, vc[k].y);
            o.z = fmaf(a3, P, vc[k].z);
            o.w = fmaf(a4, P, vc[k].w);
            __builtin_nontemporal_store(o, &yp[(k << 8) + (wv << 6) + lane]);
        }

        // ---- advance pipeline ----
        if (g < GENS - 1) {
            #pragma unroll
            for (int k = 0; k < CH; ++k) vc[k] = vn[k];
        }
    }
}

extern "C" void kernel_launch(void* const* d_in, const int* in_sizes, int n_in,
                              void* d_out, int out_size, void* d_ws, size_t ws_size,
                              hipStream_t stream) {
    const float* x = (const float*)d_in[0];
    const float* w = (const float*)d_in[1];
    float* y = (float*)d_out;

    ema_persist_kernel<<<GRID, BLOCK, 0, stream>>>(x, w, y);
}

// Round 14
// 232.576 us; speedup vs baseline: 1.0199x; 1.0010x over previous
//
#include <hip/hip_runtime.h>

// EMA along T: y[0]=x[0]; y[t] = s*x[t] + (1-s)*y[t-1].
// x: [B, C, T] f32, weights: [C] f32 (clamped to [0,1]). B=16, C=512, T=4096.
//
// Persistent, wave-independent, BARRIER-FREE streaming scan.
// 1024 blocks x 256 thr = 4096 waves; each wave owns 2 consecutive rows =
// 8 items (tiles) of 1024 elements, processed sequentially with an EXACT
// in-register carry E across tiles (reset at each row start). No LDS, no
// __syncthreads, no halo.
//
// Double-buffered software pipeline: tile j+1's 4 coalesced float4 loads
// (chunk k: float4 index rbase + j*256 + k*64 + lane -> 64x16B contiguous)
// are issued BEFORE tile j's scan. With no barrier anywhere, the compiler
// emits counted vmcnt(N) waits (not a vmcnt(0) drain -- rounds 3-13 showed
// every __syncthreads kills prefetch via the mandatory full drain before
// s_barrier), so each wave alternates load-bursts / compute / nt-store-
// bursts continuously, like the 6.3 TB/s copy microbenchmark.
//
// Per tile: per-chunk 3-FMA local scan (zero-carry) -> 6-step weighted
// Hillis-Steele over 64 lanes (step weight a^4, 4 chunks interleaved) ->
// fixup P = within-chunk prefix + (a^4)^lane * E, y = l + a^(j+1)*P ->
// non-temporal stores (y never re-read); E advances per chunk by
// E = a^256 * E + chunk_total (shfl lane-63 broadcast).

constexpr int T_LEN = 4096;
constexpr int C_LEN = 512;
constexpr int BLOCK = 256;     // 4 independent waves per block
constexpr int GRID  = 1024;    // 4096 waves total
constexpr int RPW   = 2;       // rows per wave;   4096*2 = 8192 rows
constexpr int NITEM = RPW * 4; // 8 tiles of 1024 elems per wave

typedef float nf4 __attribute__((ext_vector_type(4)));

__global__ __launch_bounds__(BLOCK) void ema_stream_kernel(
    const float* __restrict__ x,
    const float* __restrict__ w,
    float* __restrict__ y)
{
    const int lane = threadIdx.x & 63;
    const int wid  = (blockIdx.x << 2) + (threadIdx.x >> 6);   // 0..4095

    const size_t rbase = (size_t)wid * RPW * 1024;   // float4 idx of row pair
    const nf4* xp = (const nf4*)x;
    nf4*       yp = (nf4*)y;

    nf4 buf[2][4];

    // ---- prologue: tile 0 loads ----
    #pragma unroll
    for (int k = 0; k < 4; ++k)
        buf[0][k] = xp[rbase + (k << 6) + lane];

    float s = 0.f, a = 0.f, a2 = 0.f, a3 = 0.f, a4 = 0.f;
    float powl = 0.f, E = 0.f;

    #pragma unroll
    for (int j = 0; j < NITEM; ++j) {
        const int tile = j & 3;

        // ---- prefetch next tile into the alternate buffer ----
        if (j + 1 < NITEM) {
            const size_t nb = rbase + (size_t)(j + 1) * 256;
            #pragma unroll
            for (int k = 0; k < 4; ++k)
                buf[(j + 1) & 1][k] = xp[nb + (k << 6) + lane];
        }

        // ---- per-row constants (tile 0 of each row) ----
        if (tile == 0) {
            const int row = wid * RPW + (j >> 2);
            const int c   = row & (C_LEN - 1);
            s  = fminf(fmaxf(w[c], 0.0f), 1.0f);
            a  = 1.0f - s;
            a2 = a * a; a3 = a2 * a; a4 = a2 * a2;
            float tq = a4; powl = 1.0f;
            #pragma unroll
            for (int b = 0; b < 6; ++b) {
                if ((lane >> b) & 1) powl *= tq;
                tq *= tq;
            }
            E = 0.0f;                       // exact state resets per row
        }

        nf4 (&vb)[4] = buf[j & 1];          // unroll-constant index

        // ---- per-chunk local scans (zero incoming carry) ----
        float S[4];
        #pragma unroll
        for (int k = 0; k < 4; ++k) {
            float l0 = s * vb[k].x;
            if (tile == 0 && k == 0 && lane == 0) l0 = vb[k].x;  // y0 = x0
            float l1 = fmaf(a, l0, s * vb[k].y);
            float l2 = fmaf(a, l1, s * vb[k].z);
            float l3 = fmaf(a, l2, s * vb[k].w);
            vb[k].x = l0; vb[k].y = l1; vb[k].z = l2; vb[k].w = l3;
            S[k] = l3;
        }

        // ---- weighted Hillis-Steele over 64 lanes (step weight a^4) ----
        float wgt = a4;
        #pragma unroll
        for (int d = 1; d < 64; d <<= 1) {
            #pragma unroll
            for (int k = 0; k < 4; ++k) {
                float up = __shfl_up(S[k], d, 64);
                if (lane >= d) S[k] = fmaf(wgt, up, S[k]);
            }
            wgt *= wgt;
        }
        // wgt == (a^4)^64 == a^256 (one chunk's span)

        // ---- fixup + nt-store; advance exact carry E per chunk ----
        const size_t ob = rbase + (size_t)j * 256;
        #pragma unroll
        for (int k = 0; k < 4; ++k) {
            float Sx   = __shfl_up(S[k], 1, 64);
            float base = (lane == 0) ? 0.0f : Sx;   // within-chunk excl prefix
            float P    = fmaf(powl, E, base);
            nf4 o;
            o.x = fmaf(a,  P, vb[k].x);
            o.y = fmaf(a2, P, vb[k].y);
            o.z = fmaf(a3, P, vb[k].z);
            o.w = fmaf(a4, P, vb[k].w);
            __builtin_nontemporal_store(o, &yp[ob + (k << 6) + lane]);

            float Tk = __shfl(S[k], 63, 64);        // chunk total
            E = fmaf(wgt, E, Tk);
        }
    }
}

extern "C" void kernel_launch(void* const* d_in, const int* in_sizes, int n_in,
                              void* d_out, int out_size, void* d_ws, size_t ws_size,
                              hipStream_t stream) {
    const float* x = (const float*)d_in[0];
    const float* w = (const float*)d_in[1];
    float* y = (float*)d_out;

    ema_stream_kernel<<<GRID, BLOCK, 0, stream>>>(x, w, y);
}